// Round 4
// baseline (378.073 us; speedup 1.0000x reference)
//
#include <hip/hip_runtime.h>

// ---------------------------------------------------------------------------
// GIN 3-layer: h_{l+1} = act((h + agg(h)) @ W + b)
// Restructured: z = act(h) @ W ; a = b + z + agg(z)   (agg commutes with W)
// Layers 2,3: agg fused into GEMM, aggregating DIRECTLY into MFMA A-fragment
// registers (no LDS, no barrier). Split-bf16 MFMA, fp32 accumulate.
// ---------------------------------------------------------------------------

typedef __attribute__((ext_vector_type(8))) short short8;
typedef __attribute__((ext_vector_type(4))) float f32x4;
typedef unsigned short ushort_t;
typedef unsigned int uint_t;

__device__ inline ushort_t bf16_rne(float f) {
  uint_t u = __float_as_uint(f);
  uint_t r = (u + 0x7FFFu + ((u >> 16) & 1u)) >> 16;
  return (ushort_t)r;
}
__device__ inline float bf16_to_f32(ushort_t h) {
  return __uint_as_float(((uint_t)h) << 16);
}

// ---- edge dtype detection: int64 (reference decl) vs int32 (JAX x64-off) ----
__global__ __launch_bounds__(256) void k_detect(const int* __restrict__ ew,
                                                int* __restrict__ flag, int E) {
  int i = blockIdx.x * 256 + threadIdx.x;
  int idx = 2 * i + 1;
  if (idx < 2 * E) {
    if (ew[idx] != 0) atomicOr(flag, 1);    // nonzero odd word => int32 layout
  }
}

// ---- CSR build (reads edges directly, no staging) ---------------------------
__global__ __launch_bounds__(256) void k_hist(const void* __restrict__ edges,
                                              const int* __restrict__ flag,
                                              int* __restrict__ counts, int E) {
  int e = blockIdx.x * 256 + threadIdx.x;
  if (e >= E) return;
  int d;
  if (*flag) d = ((const int*)edges)[E + e];
  else       d = (int)((const long long*)edges)[E + e];
  atomicAdd(&counts[d], 1);
}

__global__ __launch_bounds__(256) void k_scan1(const int* __restrict__ counts,
                                               int* __restrict__ offs,
                                               int* __restrict__ bsum, int N) {
  __shared__ int s[256];
  int t = threadIdx.x;
  int base = blockIdx.x * 1024 + t * 4;
  int c0 = 0, c1 = 0, c2 = 0, c3 = 0;
  if (base + 0 < N) c0 = counts[base + 0];
  if (base + 1 < N) c1 = counts[base + 1];
  if (base + 2 < N) c2 = counts[base + 2];
  if (base + 3 < N) c3 = counts[base + 3];
  int mySum = c0 + c1 + c2 + c3;
  s[t] = mySum;
  __syncthreads();
  for (int d = 1; d < 256; d <<= 1) {
    int v = (t >= d) ? s[t - d] : 0;
    __syncthreads();
    s[t] += v;
    __syncthreads();
  }
  int excl = s[t] - mySum;
  if (base + 0 < N) offs[base + 0] = excl;
  if (base + 1 < N) offs[base + 1] = excl + c0;
  if (base + 2 < N) offs[base + 2] = excl + c0 + c1;
  if (base + 3 < N) offs[base + 3] = excl + c0 + c1 + c2;
  if (t == 255) bsum[blockIdx.x] = s[255];
}

__global__ __launch_bounds__(128) void k_scan2(int* __restrict__ bsum, int nb) {
  __shared__ int s[128];
  int t = threadIdx.x;
  int v = (t < nb) ? bsum[t] : 0;
  s[t] = v;
  __syncthreads();
  for (int d = 1; d < 128; d <<= 1) {
    int u = (t >= d) ? s[t - d] : 0;
    __syncthreads();
    s[t] += u;
    __syncthreads();
  }
  if (t < nb) bsum[t] = s[t] - v;
}

__global__ __launch_bounds__(256) void k_scan3(int* __restrict__ offs,
                                               const int* __restrict__ bsum,
                                               int* __restrict__ cursor,
                                               int N, int E) {
  int t = threadIdx.x;
  int add = bsum[blockIdx.x];
  int base = blockIdx.x * 1024 + t * 4;
#pragma unroll
  for (int j = 0; j < 4; j++) {
    int i = base + j;
    if (i < N) { int v = offs[i] + add; offs[i] = v; cursor[i] = v; }
  }
  if (blockIdx.x == 0 && t == 0) offs[N] = E;
}

__global__ __launch_bounds__(256) void k_fill(const void* __restrict__ edges,
                                              const int* __restrict__ flag,
                                              int* __restrict__ cursor,
                                              int* __restrict__ csr, int E) {
  int e = blockIdx.x * 256 + threadIdx.x;
  if (e >= E) return;
  int s, d;
  if (*flag) {
    const int* p = (const int*)edges;
    s = p[e]; d = p[E + e];
  } else {
    const long long* p = (const long long*)edges;
    s = (int)p[e]; d = (int)p[E + e];
  }
  int pos = atomicAdd(&cursor[d], 1);
  csr[pos] = s;
}

// ---- W repack into MFMA B-fragment order (hi/lo split bf16) -----------------
// rep[((ks*NT + tile)*64 + lane)*8 + j] = W[ks*32 + (lane>>4)*8 + j][tile*16 + (lane&15)]
__global__ __launch_bounds__(256) void k_repack(
    const float* __restrict__ W1, const float* __restrict__ W2,
    const float* __restrict__ W3,
    ushort_t* __restrict__ h1, ushort_t* __restrict__ l1,
    ushort_t* __restrict__ h2, ushort_t* __restrict__ l2,
    ushort_t* __restrict__ h3, ushort_t* __restrict__ l3) {
  int idx = blockIdx.x * 256 + threadIdx.x;
  const float* W; ushort_t* H; ushort_t* L; int NC; int i;
  if (idx < 16384)      { W = W1; H = h1; L = l1; NC = 128; i = idx; }
  else if (idx < 32768) { W = W2; H = h2; L = l2; NC = 128; i = idx - 16384; }
  else if (idx < 40960) { W = W3; H = h3; L = l3; NC = 64;  i = idx - 32768; }
  else return;
  int j = i & 7;
  int lane = (i >> 3) & 63;
  int NT = NC >> 4;
  int tile = (i >> 9) & (NT - 1);
  int ks = i >> (9 + (NC == 128 ? 3 : 2));
  int k = ks * 32 + (lane >> 4) * 8 + j;
  int n = tile * 16 + (lane & 15);
  float v = W[(size_t)k * NC + n];
  ushort_t hi = bf16_rne(v);
  ushort_t lo = bf16_rne(v - bf16_to_f32(hi));
  H[i] = hi; L[i] = lo;
}

// ---- split-bf16 MFMA GEMM (layer 1): Z = A @ W, A read from global ----------
template <int NC, bool RELU>
__global__ __launch_bounds__(256) void k_gemm_mfma(
    const float* __restrict__ A, const ushort_t* __restrict__ Bhi,
    const ushort_t* __restrict__ Blo, float* __restrict__ Z, int M) {
  constexpr int NT = NC / 16;
  int lane = threadIdx.x & 63;
  int wave = threadIdx.x >> 6;
  int row0 = blockIdx.x * 64 + wave * 16;
  int m = lane & 15;
  int q = lane >> 4;
  int grow = row0 + m;
  bool rowok = (grow < M);

  f32x4 acc[NT];
#pragma unroll
  for (int t = 0; t < NT; t++) { acc[t][0] = 0.f; acc[t][1] = 0.f; acc[t][2] = 0.f; acc[t][3] = 0.f; }

  const float* arow = A + (size_t)(rowok ? grow : 0) * 128 + q * 8;

#pragma unroll
  for (int ks = 0; ks < 4; ks++) {
    float av[8];
    *(float4*)(av)     = *(const float4*)(arow + ks * 32);
    *(float4*)(av + 4) = *(const float4*)(arow + ks * 32 + 4);
    short8 ahi, alo;
#pragma unroll
    for (int j = 0; j < 8; j++) {
      float v = RELU ? fmaxf(av[j], 0.f) : av[j];
      ushort_t hi = bf16_rne(v);
      ahi[j] = (short)hi;
      alo[j] = (short)bf16_rne(v - bf16_to_f32(hi));
    }
#pragma unroll
    for (int t = 0; t < NT; t++) {
      const short8 bh = *(const short8*)(Bhi + (((size_t)ks * NT + t) * 64 + lane) * 8);
      const short8 bl = *(const short8*)(Blo + (((size_t)ks * NT + t) * 64 + lane) * 8);
      acc[t] = __builtin_amdgcn_mfma_f32_16x16x32_bf16(ahi, bh, acc[t], 0, 0, 0);
      acc[t] = __builtin_amdgcn_mfma_f32_16x16x32_bf16(ahi, bl, acc[t], 0, 0, 0);
      acc[t] = __builtin_amdgcn_mfma_f32_16x16x32_bf16(alo, bh, acc[t], 0, 0, 0);
    }
  }

  int zrow = row0 + q * 4;
#pragma unroll
  for (int r = 0; r < 4; r++) {
    if (zrow + r < M) {
#pragma unroll
      for (int t = 0; t < NT; t++)
        Z[(size_t)(zrow + r) * NC + t * 16 + m] = acc[t][r];
    }
  }
}

// ---- fused agg + GEMM (layers 2,3), register-direct, no LDS -----------------
// Lane (m = lane&15, q = lane>>4) aggregates a[row][k], k = ks*32+q*8+j,
// straight into 32 fp32 regs = its MFMA A-fragment slice. The 4 lanes sharing
// a row together read each gathered 512B source row exactly once.
template <int NC>
__global__ __launch_bounds__(256, 4) void k_fused(
    const float* __restrict__ Zin, const int* __restrict__ csr,
    const int* __restrict__ offs, const float* __restrict__ bias,
    const ushort_t* __restrict__ Bhi, const ushort_t* __restrict__ Blo,
    float* __restrict__ Zout, int M) {
  constexpr int NT = NC / 16;
  int lane = threadIdx.x & 63;
  int wave = threadIdx.x >> 6;
  int row0 = blockIdx.x * 64 + wave * 16;
  int m = lane & 15;
  int q = lane >> 4;
  int grow = row0 + m;
  bool rowok = (grow < M);

  // a[grow][ks*32 + q*8 + j] accumulators, init = bias + Zin[grow]
  float av[4][8];
  const float* zr0 = Zin + (size_t)(rowok ? grow : 0) * 128 + q * 8;
  const float* bq = bias + q * 8;
#pragma unroll
  for (int ks = 0; ks < 4; ks++) {
    float4 b0 = *(const float4*)(bq + ks * 32);
    float4 b1 = *(const float4*)(bq + ks * 32 + 4);
    float4 z0 = *(const float4*)(zr0 + ks * 32);
    float4 z1 = *(const float4*)(zr0 + ks * 32 + 4);
    av[ks][0] = b0.x + z0.x; av[ks][1] = b0.y + z0.y;
    av[ks][2] = b0.z + z0.z; av[ks][3] = b0.w + z0.w;
    av[ks][4] = b1.x + z1.x; av[ks][5] = b1.y + z1.y;
    av[ks][6] = b1.z + z1.z; av[ks][7] = b1.w + z1.w;
  }

  int s = 0, e = 0;
  if (rowok) { s = offs[grow]; e = offs[grow + 1]; }
  for (int j = s; j < e; j++) {
    int idx = csr[j];
    const float* zr = Zin + (size_t)idx * 128 + q * 8;
#pragma unroll
    for (int ks = 0; ks < 4; ks++) {
      float4 u0 = *(const float4*)(zr + ks * 32);
      float4 u1 = *(const float4*)(zr + ks * 32 + 4);
      av[ks][0] += u0.x; av[ks][1] += u0.y; av[ks][2] += u0.z; av[ks][3] += u0.w;
      av[ks][4] += u1.x; av[ks][5] += u1.y; av[ks][6] += u1.z; av[ks][7] += u1.w;
    }
  }

  // relu + split-bf16 + MFMA
  f32x4 acc[NT];
#pragma unroll
  for (int tt = 0; tt < NT; tt++) { acc[tt][0] = 0.f; acc[tt][1] = 0.f; acc[tt][2] = 0.f; acc[tt][3] = 0.f; }

#pragma unroll
  for (int ks = 0; ks < 4; ks++) {
    short8 ahi, alo;
#pragma unroll
    for (int j = 0; j < 8; j++) {
      float v = fmaxf(av[ks][j], 0.f);
      ushort_t hi = bf16_rne(v);
      ahi[j] = (short)hi;
      alo[j] = (short)bf16_rne(v - bf16_to_f32(hi));
    }
#pragma unroll
    for (int tt = 0; tt < NT; tt++) {
      const short8 bh = *(const short8*)(Bhi + (((size_t)ks * NT + tt) * 64 + lane) * 8);
      const short8 bl = *(const short8*)(Blo + (((size_t)ks * NT + tt) * 64 + lane) * 8);
      acc[tt] = __builtin_amdgcn_mfma_f32_16x16x32_bf16(ahi, bh, acc[tt], 0, 0, 0);
      acc[tt] = __builtin_amdgcn_mfma_f32_16x16x32_bf16(ahi, bl, acc[tt], 0, 0, 0);
      acc[tt] = __builtin_amdgcn_mfma_f32_16x16x32_bf16(alo, bh, acc[tt], 0, 0, 0);
    }
  }

  int zrow = row0 + q * 4;
#pragma unroll
  for (int r = 0; r < 4; r++) {
    if (zrow + r < M) {
#pragma unroll
      for (int tt = 0; tt < NT; tt++)
        Zout[(size_t)(zrow + r) * NC + tt * 16 + m] = acc[tt][r];
    }
  }
}

// ---- final CSR aggregation (64 cols): out = b + z + agg(z) ------------------
__global__ __launch_bounds__(256) void k_agg64(const float* __restrict__ z,
                                               const int* __restrict__ csr,
                                               const int* __restrict__ offs,
                                               const float* __restrict__ bias,
                                               float* __restrict__ out, int N) {
  int t = threadIdx.x;
  int node = blockIdx.x * 16 + (t >> 4);
  if (node >= N) return;
  int c = (t & 15) * 4;
  float4 v = *(const float4*)&z[(size_t)node * 64 + c];
  float4 b = *(const float4*)&bias[c];
  v.x += b.x; v.y += b.y; v.z += b.z; v.w += b.w;
  int s = offs[node], e = offs[node + 1];
  int j = s;
  for (; j + 4 <= e; j += 4) {
    int i0 = csr[j], i1 = csr[j + 1], i2 = csr[j + 2], i3 = csr[j + 3];
    float4 u0 = *(const float4*)&z[(size_t)i0 * 64 + c];
    float4 u1 = *(const float4*)&z[(size_t)i1 * 64 + c];
    float4 u2 = *(const float4*)&z[(size_t)i2 * 64 + c];
    float4 u3 = *(const float4*)&z[(size_t)i3 * 64 + c];
    v.x += u0.x + u1.x + u2.x + u3.x;
    v.y += u0.y + u1.y + u2.y + u3.y;
    v.z += u0.z + u1.z + u2.z + u3.z;
    v.w += u0.w + u1.w + u2.w + u3.w;
  }
  for (; j < e; j++) {
    int i0 = csr[j];
    float4 u = *(const float4*)&z[(size_t)i0 * 64 + c];
    v.x += u.x; v.y += u.y; v.z += u.z; v.w += u.w;
  }
  *(float4*)&out[(size_t)node * 64 + c] = v;
}

// ---------------------------------------------------------------------------
extern "C" void kernel_launch(void* const* d_in, const int* in_sizes, int n_in,
                              void* d_out, int out_size, void* d_ws, size_t ws_size,
                              hipStream_t stream) {
  const float* x  = (const float*)d_in[0];
  const void* edges = d_in[1];
  const float* W1 = (const float*)d_in[2];
  const float* b1 = (const float*)d_in[3];
  const float* W2 = (const float*)d_in[4];
  const float* b2 = (const float*)d_in[5];
  const float* W3 = (const float*)d_in[6];
  const float* b3 = (const float*)d_in[7];
  float* out = (float*)d_out;

  int N = in_sizes[0] / 128;   // 100000
  int E = in_sizes[1] / 2;     // 600000

  char* w = (char*)d_ws;
  size_t off = 0;
  auto alloc = [&](size_t bytes) -> void* {
    void* p = w + off;
    off = (off + bytes + 255) & ~(size_t)255;
    return p;
  };
  size_t curBytes = ((size_t)N * 4 + 255) & ~(size_t)255;
  int*   cursor = (int*)alloc(curBytes);     // degree counts, then fill cursor
  int*   flag   = (int*)alloc(4);            // adjacent: one memset covers both
  int*   csr    = (int*)alloc((size_t)E * 4);
  int*   offs   = (int*)alloc((size_t)(N + 1) * 4);
  int*   bsum   = (int*)alloc(4096);
  ushort_t* h1  = (ushort_t*)alloc(16384 * 2);
  ushort_t* l1  = (ushort_t*)alloc(16384 * 2);
  ushort_t* h2  = (ushort_t*)alloc(16384 * 2);
  ushort_t* l2  = (ushort_t*)alloc(16384 * 2);
  ushort_t* h3  = (ushort_t*)alloc(8192 * 2);
  ushort_t* l3  = (ushort_t*)alloc(8192 * 2);
  float* z1     = (float*)alloc((size_t)N * 128 * 4);
  float* z2     = (float*)alloc((size_t)N * 128 * 4);
  float* z3     = z1;                         // reuse (N x 64 fits)

  int ge = (E + 255) / 256;
  int nb = (N + 1023) / 1024;

  hipMemsetAsync(cursor, 0, curBytes + 4, stream);
  k_detect<<<4, 256, 0, stream>>>((const int*)edges, flag, E);
  k_hist<<<ge, 256, 0, stream>>>(edges, flag, cursor, E);
  k_scan1<<<nb, 256, 0, stream>>>(cursor, offs, bsum, N);
  k_scan2<<<1, 128, 0, stream>>>(bsum, nb);
  k_scan3<<<nb, 256, 0, stream>>>(offs, bsum, cursor, N, E);
  k_fill<<<ge, 256, 0, stream>>>(edges, flag, cursor, csr, E);
  k_repack<<<160, 256, 0, stream>>>(W1, W2, W3, h1, l1, h2, l2, h3, l3);

  int gm = (N + 63) / 64;
  // layer 1: z1 = x @ W1
  k_gemm_mfma<128, false><<<gm, 256, 0, stream>>>(x, h1, l1, z1, N);
  // layer 2 fused: a1 = b1 + z1 + agg(z1) (regs); z2 = relu(a1) @ W2
  k_fused<128><<<gm, 256, 0, stream>>>(z1, csr, offs, b1, h2, l2, z2, N);
  // layer 3 fused: a2 = b2 + z2 + agg(z2) (regs); z3 = relu(a2) @ W3
  k_fused<64><<<gm, 256, 0, stream>>>(z2, csr, offs, b2, h3, l3, z3, N);
  // final agg: out = b3 + z3 + agg(z3)
  k_agg64<<<(N + 15) / 16, 256, 0, stream>>>(z3, csr, offs, b3, out, N);
}

// Round 5
// 300.646 us; speedup vs baseline: 1.2575x; 1.2575x over previous
//
#include <hip/hip_runtime.h>

// ---------------------------------------------------------------------------
// GIN 3-layer: h_{l+1} = act((h + agg(h)) @ W + b)
// Restructured: z = act(h) @ W ; a = b + z + agg(z)   (agg commutes with W)
// Intermediates z stored BF16 (halves gather traffic); aggregation in fp32
// registers; GEMM = split-bf16 MFMA (hi*hi + hi*lo + lo*hi, fp32 acc).
// Layers 2,3 fused: gather directly into MFMA A-fragment registers.
// ---------------------------------------------------------------------------

typedef __attribute__((ext_vector_type(8))) short short8;
typedef __attribute__((ext_vector_type(4))) float f32x4;
typedef unsigned short ushort_t;
typedef unsigned int uint_t;

__device__ inline ushort_t bf16_rne(float f) {
  uint_t u = __float_as_uint(f);
  uint_t r = (u + 0x7FFFu + ((u >> 16) & 1u)) >> 16;
  return (ushort_t)r;
}
__device__ inline float bf16_to_f32(ushort_t h) {
  return __uint_as_float(((uint_t)h) << 16);
}

// ---- edge dtype detection: int64 (reference decl) vs int32 (JAX x64-off) ----
__global__ __launch_bounds__(256) void k_detect(const int* __restrict__ ew,
                                                int* __restrict__ flag, int E) {
  int i = blockIdx.x * 256 + threadIdx.x;
  int idx = 2 * i + 1;
  if (idx < 2 * E) {
    if (ew[idx] != 0) atomicOr(flag, 1);    // nonzero odd word => int32 layout
  }
}

// ---- CSR build (reads edges directly, no staging) ---------------------------
__global__ __launch_bounds__(256) void k_hist(const void* __restrict__ edges,
                                              const int* __restrict__ flag,
                                              int* __restrict__ counts, int E) {
  int e = blockIdx.x * 256 + threadIdx.x;
  if (e >= E) return;
  int d;
  if (*flag) d = ((const int*)edges)[E + e];
  else       d = (int)((const long long*)edges)[E + e];
  atomicAdd(&counts[d], 1);
}

__global__ __launch_bounds__(256) void k_scan1(const int* __restrict__ counts,
                                               int* __restrict__ offs,
                                               int* __restrict__ bsum, int N) {
  __shared__ int s[256];
  int t = threadIdx.x;
  int base = blockIdx.x * 1024 + t * 4;
  int c0 = 0, c1 = 0, c2 = 0, c3 = 0;
  if (base + 0 < N) c0 = counts[base + 0];
  if (base + 1 < N) c1 = counts[base + 1];
  if (base + 2 < N) c2 = counts[base + 2];
  if (base + 3 < N) c3 = counts[base + 3];
  int mySum = c0 + c1 + c2 + c3;
  s[t] = mySum;
  __syncthreads();
  for (int d = 1; d < 256; d <<= 1) {
    int v = (t >= d) ? s[t - d] : 0;
    __syncthreads();
    s[t] += v;
    __syncthreads();
  }
  int excl = s[t] - mySum;
  if (base + 0 < N) offs[base + 0] = excl;
  if (base + 1 < N) offs[base + 1] = excl + c0;
  if (base + 2 < N) offs[base + 2] = excl + c0 + c1;
  if (base + 3 < N) offs[base + 3] = excl + c0 + c1 + c2;
  if (t == 255) bsum[blockIdx.x] = s[255];
}

__global__ __launch_bounds__(128) void k_scan2(int* __restrict__ bsum, int nb) {
  __shared__ int s[128];
  int t = threadIdx.x;
  int v = (t < nb) ? bsum[t] : 0;
  s[t] = v;
  __syncthreads();
  for (int d = 1; d < 128; d <<= 1) {
    int u = (t >= d) ? s[t - d] : 0;
    __syncthreads();
    s[t] += u;
    __syncthreads();
  }
  if (t < nb) bsum[t] = s[t] - v;
}

__global__ __launch_bounds__(256) void k_scan3(int* __restrict__ offs,
                                               const int* __restrict__ bsum,
                                               int* __restrict__ cursor,
                                               int N, int E) {
  int t = threadIdx.x;
  int add = bsum[blockIdx.x];
  int base = blockIdx.x * 1024 + t * 4;
#pragma unroll
  for (int j = 0; j < 4; j++) {
    int i = base + j;
    if (i < N) { int v = offs[i] + add; offs[i] = v; cursor[i] = v; }
  }
  if (blockIdx.x == 0 && t == 0) offs[N] = E;
}

__global__ __launch_bounds__(256) void k_fill(const void* __restrict__ edges,
                                              const int* __restrict__ flag,
                                              int* __restrict__ cursor,
                                              int* __restrict__ csr, int E) {
  int e = blockIdx.x * 256 + threadIdx.x;
  if (e >= E) return;
  int s, d;
  if (*flag) {
    const int* p = (const int*)edges;
    s = p[e]; d = p[E + e];
  } else {
    const long long* p = (const long long*)edges;
    s = (int)p[e]; d = (int)p[E + e];
  }
  int pos = atomicAdd(&cursor[d], 1);
  csr[pos] = s;
}

// ---- W repack into MFMA B-fragment order (hi/lo split bf16) -----------------
__global__ __launch_bounds__(256) void k_repack(
    const float* __restrict__ W1, const float* __restrict__ W2,
    const float* __restrict__ W3,
    ushort_t* __restrict__ h1, ushort_t* __restrict__ l1,
    ushort_t* __restrict__ h2, ushort_t* __restrict__ l2,
    ushort_t* __restrict__ h3, ushort_t* __restrict__ l3) {
  int idx = blockIdx.x * 256 + threadIdx.x;
  const float* W; ushort_t* H; ushort_t* L; int NC; int i;
  if (idx < 16384)      { W = W1; H = h1; L = l1; NC = 128; i = idx; }
  else if (idx < 32768) { W = W2; H = h2; L = l2; NC = 128; i = idx - 16384; }
  else if (idx < 40960) { W = W3; H = h3; L = l3; NC = 64;  i = idx - 32768; }
  else return;
  int j = i & 7;
  int lane = (i >> 3) & 63;
  int NT = NC >> 4;
  int tile = (i >> 9) & (NT - 1);
  int ks = i >> (9 + (NC == 128 ? 3 : 2));
  int k = ks * 32 + (lane >> 4) * 8 + j;
  int n = tile * 16 + (lane & 15);
  float v = W[(size_t)k * NC + n];
  ushort_t hi = bf16_rne(v);
  ushort_t lo = bf16_rne(v - bf16_to_f32(hi));
  H[i] = hi; L[i] = lo;
}

// ---- layer 1 GEMM: Z(bf16)[M x NC] = A(fp32)[M x 128] @ W -------------------
template <int NC>
__global__ __launch_bounds__(256) void k_gemm_mfma(
    const float* __restrict__ A, const ushort_t* __restrict__ Bhi,
    const ushort_t* __restrict__ Blo, ushort_t* __restrict__ Z, int M) {
  constexpr int NT = NC / 16;
  int lane = threadIdx.x & 63;
  int wave = threadIdx.x >> 6;
  int row0 = blockIdx.x * 64 + wave * 16;
  int m = lane & 15;
  int q = lane >> 4;
  int grow = row0 + m;
  bool rowok = (grow < M);

  f32x4 acc[NT];
#pragma unroll
  for (int t = 0; t < NT; t++) { acc[t][0] = 0.f; acc[t][1] = 0.f; acc[t][2] = 0.f; acc[t][3] = 0.f; }

  const float* arow = A + (size_t)(rowok ? grow : 0) * 128 + q * 8;

#pragma unroll
  for (int ks = 0; ks < 4; ks++) {
    float av[8];
    *(float4*)(av)     = *(const float4*)(arow + ks * 32);
    *(float4*)(av + 4) = *(const float4*)(arow + ks * 32 + 4);
    short8 ahi, alo;
#pragma unroll
    for (int j = 0; j < 8; j++) {
      float v = av[j];
      ushort_t hi = bf16_rne(v);
      ahi[j] = (short)hi;
      alo[j] = (short)bf16_rne(v - bf16_to_f32(hi));
    }
#pragma unroll
    for (int t = 0; t < NT; t++) {
      const short8 bh = *(const short8*)(Bhi + (((size_t)ks * NT + t) * 64 + lane) * 8);
      const short8 bl = *(const short8*)(Blo + (((size_t)ks * NT + t) * 64 + lane) * 8);
      acc[t] = __builtin_amdgcn_mfma_f32_16x16x32_bf16(ahi, bh, acc[t], 0, 0, 0);
      acc[t] = __builtin_amdgcn_mfma_f32_16x16x32_bf16(ahi, bl, acc[t], 0, 0, 0);
      acc[t] = __builtin_amdgcn_mfma_f32_16x16x32_bf16(alo, bh, acc[t], 0, 0, 0);
    }
  }

  int zrow = row0 + q * 4;
#pragma unroll
  for (int r = 0; r < 4; r++) {
    if (zrow + r < M) {
#pragma unroll
      for (int t = 0; t < NT; t++)
        Z[(size_t)(zrow + r) * NC + t * 16 + m] = bf16_rne(acc[t][r]);
    }
  }
}

// ---- fused agg + GEMM (layers 2,3): bf16 z in, bf16 z out -------------------
// Lane (m, q) aggregates a[row][ks*32+q*8+j] in fp32 regs from bf16 z rows
// (4x dwordx4 per gathered row per lane; edge loop unrolled x2 -> 8 loads
// in flight), then relu + hi/lo split + MFMA.
template <int NC>
__global__ __launch_bounds__(256, 4) void k_fused(
    const ushort_t* __restrict__ Zin, const int* __restrict__ csr,
    const int* __restrict__ offs, const float* __restrict__ bias,
    const ushort_t* __restrict__ Bhi, const ushort_t* __restrict__ Blo,
    ushort_t* __restrict__ Zout, int M) {
  constexpr int NT = NC / 16;
  int lane = threadIdx.x & 63;
  int wave = threadIdx.x >> 6;
  int row0 = blockIdx.x * 64 + wave * 16;
  int m = lane & 15;
  int q = lane >> 4;
  int grow = row0 + m;
  bool rowok = (grow < M);

  // accumulators a[grow][ks*32 + q*8 + j], init = bias + Zin[grow]
  float av[4][8];
  const ushort_t* zr0 = Zin + (size_t)(rowok ? grow : 0) * 128 + q * 8;
  const float* bq = bias + q * 8;
#pragma unroll
  for (int ks = 0; ks < 4; ks++) {
    float4 b0 = *(const float4*)(bq + ks * 32);
    float4 b1 = *(const float4*)(bq + ks * 32 + 4);
    short8 u = *(const short8*)(zr0 + ks * 32);
    av[ks][0] = b0.x + bf16_to_f32((ushort_t)u[0]);
    av[ks][1] = b0.y + bf16_to_f32((ushort_t)u[1]);
    av[ks][2] = b0.z + bf16_to_f32((ushort_t)u[2]);
    av[ks][3] = b0.w + bf16_to_f32((ushort_t)u[3]);
    av[ks][4] = b1.x + bf16_to_f32((ushort_t)u[4]);
    av[ks][5] = b1.y + bf16_to_f32((ushort_t)u[5]);
    av[ks][6] = b1.z + bf16_to_f32((ushort_t)u[6]);
    av[ks][7] = b1.w + bf16_to_f32((ushort_t)u[7]);
  }

  int s = 0, e = 0;
  if (rowok) { s = offs[grow]; e = offs[grow + 1]; }
  int j = s;
  for (; j + 2 <= e; j += 2) {
    int i0 = csr[j], i1 = csr[j + 1];
    const ushort_t* za = Zin + (size_t)i0 * 128 + q * 8;
    const ushort_t* zb = Zin + (size_t)i1 * 128 + q * 8;
    short8 ua[4], ub[4];
#pragma unroll
    for (int ks = 0; ks < 4; ks++) ua[ks] = *(const short8*)(za + ks * 32);
#pragma unroll
    for (int ks = 0; ks < 4; ks++) ub[ks] = *(const short8*)(zb + ks * 32);
#pragma unroll
    for (int ks = 0; ks < 4; ks++)
#pragma unroll
      for (int jj = 0; jj < 8; jj++)
        av[ks][jj] += bf16_to_f32((ushort_t)ua[ks][jj]) +
                      bf16_to_f32((ushort_t)ub[ks][jj]);
  }
  if (j < e) {
    int i0 = csr[j];
    const ushort_t* za = Zin + (size_t)i0 * 128 + q * 8;
#pragma unroll
    for (int ks = 0; ks < 4; ks++) {
      short8 u = *(const short8*)(za + ks * 32);
#pragma unroll
      for (int jj = 0; jj < 8; jj++)
        av[ks][jj] += bf16_to_f32((ushort_t)u[jj]);
    }
  }

  // relu + split-bf16 + MFMA
  f32x4 acc[NT];
#pragma unroll
  for (int tt = 0; tt < NT; tt++) { acc[tt][0] = 0.f; acc[tt][1] = 0.f; acc[tt][2] = 0.f; acc[tt][3] = 0.f; }

#pragma unroll
  for (int ks = 0; ks < 4; ks++) {
    short8 ahi, alo;
#pragma unroll
    for (int jj = 0; jj < 8; jj++) {
      float v = fmaxf(av[ks][jj], 0.f);
      ushort_t hi = bf16_rne(v);
      ahi[jj] = (short)hi;
      alo[jj] = (short)bf16_rne(v - bf16_to_f32(hi));
    }
#pragma unroll
    for (int tt = 0; tt < NT; tt++) {
      const short8 bh = *(const short8*)(Bhi + (((size_t)ks * NT + tt) * 64 + lane) * 8);
      const short8 bl = *(const short8*)(Blo + (((size_t)ks * NT + tt) * 64 + lane) * 8);
      acc[tt] = __builtin_amdgcn_mfma_f32_16x16x32_bf16(ahi, bh, acc[tt], 0, 0, 0);
      acc[tt] = __builtin_amdgcn_mfma_f32_16x16x32_bf16(ahi, bl, acc[tt], 0, 0, 0);
      acc[tt] = __builtin_amdgcn_mfma_f32_16x16x32_bf16(alo, bh, acc[tt], 0, 0, 0);
    }
  }

  int zrow = row0 + q * 4;
#pragma unroll
  for (int r = 0; r < 4; r++) {
    if (zrow + r < M) {
#pragma unroll
      for (int tt = 0; tt < NT; tt++)
        Zout[(size_t)(zrow + r) * NC + tt * 16 + m] = bf16_rne(acc[tt][r]);
    }
  }
}

// ---- final agg (64 cols, bf16 z in, fp32 out): out = b + z + agg(z) ---------
// 8 lanes per node, 8 bf16 cols each (16B loads); edge loop unrolled x4.
__global__ __launch_bounds__(256) void k_agg64(const ushort_t* __restrict__ z,
                                               const int* __restrict__ csr,
                                               const int* __restrict__ offs,
                                               const float* __restrict__ bias,
                                               float* __restrict__ out, int N) {
  int t = threadIdx.x;
  int node = blockIdx.x * 32 + (t >> 3);
  if (node >= N) return;
  int c = (t & 7) * 8;
  float acc[8];
  {
    short8 u = *(const short8*)(z + (size_t)node * 64 + c);
#pragma unroll
    for (int jj = 0; jj < 8; jj++)
      acc[jj] = bias[c + jj] + bf16_to_f32((ushort_t)u[jj]);
  }
  int s = offs[node], e = offs[node + 1];
  int j = s;
  for (; j + 4 <= e; j += 4) {
    int i0 = csr[j], i1 = csr[j + 1], i2 = csr[j + 2], i3 = csr[j + 3];
    short8 u0 = *(const short8*)(z + (size_t)i0 * 64 + c);
    short8 u1 = *(const short8*)(z + (size_t)i1 * 64 + c);
    short8 u2 = *(const short8*)(z + (size_t)i2 * 64 + c);
    short8 u3 = *(const short8*)(z + (size_t)i3 * 64 + c);
#pragma unroll
    for (int jj = 0; jj < 8; jj++)
      acc[jj] += (bf16_to_f32((ushort_t)u0[jj]) + bf16_to_f32((ushort_t)u1[jj])) +
                 (bf16_to_f32((ushort_t)u2[jj]) + bf16_to_f32((ushort_t)u3[jj]));
  }
  for (; j < e; j++) {
    int i0 = csr[j];
    short8 u = *(const short8*)(z + (size_t)i0 * 64 + c);
#pragma unroll
    for (int jj = 0; jj < 8; jj++)
      acc[jj] += bf16_to_f32((ushort_t)u[jj]);
  }
  float4 o0 = make_float4(acc[0], acc[1], acc[2], acc[3]);
  float4 o1 = make_float4(acc[4], acc[5], acc[6], acc[7]);
  *(float4*)&out[(size_t)node * 64 + c]     = o0;
  *(float4*)&out[(size_t)node * 64 + c + 4] = o1;
}

// ---------------------------------------------------------------------------
extern "C" void kernel_launch(void* const* d_in, const int* in_sizes, int n_in,
                              void* d_out, int out_size, void* d_ws, size_t ws_size,
                              hipStream_t stream) {
  const float* x  = (const float*)d_in[0];
  const void* edges = d_in[1];
  const float* W1 = (const float*)d_in[2];
  const float* b1 = (const float*)d_in[3];
  const float* W2 = (const float*)d_in[4];
  const float* b2 = (const float*)d_in[5];
  const float* W3 = (const float*)d_in[6];
  const float* b3 = (const float*)d_in[7];
  float* out = (float*)d_out;

  int N = in_sizes[0] / 128;   // 100000
  int E = in_sizes[1] / 2;     // 600000

  char* w = (char*)d_ws;
  size_t off = 0;
  auto alloc = [&](size_t bytes) -> void* {
    void* p = w + off;
    off = (off + bytes + 255) & ~(size_t)255;
    return p;
  };
  size_t curBytes = ((size_t)N * 4 + 255) & ~(size_t)255;
  int*   cursor = (int*)alloc(curBytes);     // degree counts, then fill cursor
  int*   flag   = (int*)alloc(4);            // adjacent: one memset covers both
  int*   csr    = (int*)alloc((size_t)E * 4);
  int*   offs   = (int*)alloc((size_t)(N + 1) * 4);
  int*   bsum   = (int*)alloc(4096);
  ushort_t* h1  = (ushort_t*)alloc(16384 * 2);
  ushort_t* l1  = (ushort_t*)alloc(16384 * 2);
  ushort_t* h2  = (ushort_t*)alloc(16384 * 2);
  ushort_t* l2  = (ushort_t*)alloc(16384 * 2);
  ushort_t* h3  = (ushort_t*)alloc(8192 * 2);
  ushort_t* l3  = (ushort_t*)alloc(8192 * 2);
  ushort_t* z1  = (ushort_t*)alloc((size_t)N * 128 * 2);  // bf16
  ushort_t* z2  = (ushort_t*)alloc((size_t)N * 128 * 2);  // bf16
  ushort_t* z3  = z1;                                     // reuse (N x 64 fits)

  int ge = (E + 255) / 256;
  int nb = (N + 1023) / 1024;

  hipMemsetAsync(cursor, 0, curBytes + 4, stream);
  k_detect<<<4, 256, 0, stream>>>((const int*)edges, flag, E);
  k_hist<<<ge, 256, 0, stream>>>(edges, flag, cursor, E);
  k_scan1<<<nb, 256, 0, stream>>>(cursor, offs, bsum, N);
  k_scan2<<<1, 128, 0, stream>>>(bsum, nb);
  k_scan3<<<nb, 256, 0, stream>>>(offs, bsum, cursor, N, E);
  k_fill<<<ge, 256, 0, stream>>>(edges, flag, cursor, csr, E);
  k_repack<<<160, 256, 0, stream>>>(W1, W2, W3, h1, l1, h2, l2, h3, l3);

  int gm = (N + 63) / 64;
  // layer 1: z1 = x @ W1   (bf16 out)
  k_gemm_mfma<128><<<gm, 256, 0, stream>>>(x, h1, l1, z1, N);
  // layer 2 fused: a1 = b1 + z1 + agg(z1) (regs); z2 = relu(a1) @ W2
  k_fused<128><<<gm, 256, 0, stream>>>(z1, csr, offs, b1, h2, l2, z2, N);
  // layer 3 fused: a2 = b2 + z2 + agg(z2) (regs); z3 = relu(a2) @ W3
  k_fused<64><<<gm, 256, 0, stream>>>(z2, csr, offs, b2, h3, l3, z3, N);
  // final agg: out = b3 + z3 + agg(z3)   (fp32 out)
  k_agg64<<<(N + 31) / 32, 256, 0, stream>>>(z3, csr, offs, b3, out, N);
}